// Round 5
// baseline (92.203 us; speedup 1.0000x reference)
//
#include <hip/hip_runtime.h>
#include <hip/hip_bf16.h>

// Problem constants (fixed by the reference file)
#define NN    4096
#define EE    4096
#define DM    256
#define EDIM  64
#define HH    8
#define DHd   32
#define LL    64

typedef short  s16x8 __attribute__((ext_vector_type(8)));
typedef unsigned short u16x8 __attribute__((ext_vector_type(8)));
typedef float  f32x4 __attribute__((ext_vector_type(4)));

#define SCALE 0.17677669529663687f   // 1/sqrt(32)

__device__ __forceinline__ float b2f(unsigned short u) {
  return __uint_as_float(((unsigned int)u) << 16);
}
__device__ __forceinline__ unsigned short f2b_bits(float f) {
  unsigned int u = __float_as_uint(f);
  u = (u + 0x7FFFu + ((u >> 16) & 1u)) >> 16;   // RNE
  return (unsigned short)u;
}

// ================= shared GEMM tile bodies (64x64 tile, 4 waves) =================
// C[i][j] = sum_k A[i][k]*B[j][k]
#define MODE_PLAIN 0
#define MODE_PROJ  1
#define MODE_OUT   2

__device__ __forceinline__ void gemm_mfma_body(
    short* As, short* Bs, f32x4 acc[2][2], int wr, int wc, int fr, int fk) {
  s16x8 af0 = *(const s16x8*)&As[(wr + fr) * 40 + fk];
  s16x8 af1 = *(const s16x8*)&As[(wr + 16 + fr) * 40 + fk];
  s16x8 bf0 = *(const s16x8*)&Bs[(wc + fr) * 40 + fk];
  s16x8 bf1 = *(const s16x8*)&Bs[(wc + 16 + fr) * 40 + fk];
  acc[0][0] = __builtin_amdgcn_mfma_f32_16x16x32_bf16(af0, bf0, acc[0][0], 0, 0, 0);
  acc[0][1] = __builtin_amdgcn_mfma_f32_16x16x32_bf16(af0, bf1, acc[0][1], 0, 0, 0);
  acc[1][0] = __builtin_amdgcn_mfma_f32_16x16x32_bf16(af1, bf0, acc[1][0], 0, 0, 0);
  acc[1][1] = __builtin_amdgcn_mfma_f32_16x16x32_bf16(af1, bf1, acc[1][1], 0, 0, 0);
}

// bf16-source version
__device__ __forceinline__ void gemm_tile(
    const unsigned short* __restrict__ A, const unsigned short* __restrict__ B,
    int i0, int j0, int N, int K, int mode,
    float* __restrict__ out_f, unsigned short* __restrict__ out_b,
    unsigned short* __restrict__ out_b2, const float* __restrict__ bias,
    short* As, short* Bs) {
  const int tid  = threadIdx.x;
  const int wid  = tid >> 6, lane = tid & 63;
  const int wr   = (wid >> 1) * 32, wc = (wid & 1) * 32;
  const int srow = tid >> 2, schunk = (tid & 3) * 8;
  const int fr   = lane & 15, fk = (lane >> 4) * 8;

  f32x4 acc[2][2];
#pragma unroll
  for (int a = 0; a < 2; ++a)
#pragma unroll
    for (int b = 0; b < 2; ++b) acc[a][b] = (f32x4){0.f, 0.f, 0.f, 0.f};

  for (int kk = 0; kk < K; kk += 32) {
    *(s16x8*)&As[srow * 40 + schunk] = *(const s16x8*)&A[(size_t)(i0 + srow) * K + kk + schunk];
    *(s16x8*)&Bs[srow * 40 + schunk] = *(const s16x8*)&B[(size_t)(j0 + srow) * K + kk + schunk];
    __syncthreads();
    gemm_mfma_body(As, Bs, acc, wr, wc, fr, fk);
    __syncthreads();
  }

  const int ecol = lane & 15, erow0 = (lane >> 4) * 4;
#pragma unroll
  for (int mi = 0; mi < 2; ++mi)
#pragma unroll
    for (int ni = 0; ni < 2; ++ni) {
#pragma unroll
      for (int v = 0; v < 4; ++v) {
        int i = i0 + wr + mi * 16 + erow0 + v;
        int j = j0 + wc + ni * 16 + ecol;
        float val = acc[mi][ni][v];
        if (mode == MODE_PLAIN) {
          out_b[(size_t)i * N + j] = f2b_bits(val);
        } else if (mode == MODE_PROJ) {
          // q (bf16, scale+bias folded) | Kn (no bias; cancels) | Vn (+bias)
          if (j < 256)      out_b[(size_t)i * 256 + j]           = f2b_bits((val + bias[j]) * SCALE);
          else if (j < 512) out_b2[(size_t)i * 256 + (j - 256)]  = f2b_bits(val);
          else              ((unsigned short*)out_f)[(size_t)i * 256 + (j - 512)] = f2b_bits(val + bias[j]);
        } else {
          float r = val + bias[j];
          out_f[(size_t)i * N + j] = r > 0.f ? r : 0.f;
        }
      }
    }
}

// f32-source version (converts to bf16 during LDS staging), MODE_PLAIN only
__device__ __forceinline__ void gemm_tile_f32src(
    const float* __restrict__ A, const float* __restrict__ B,
    int i0, int j0, int N, int K,
    unsigned short* __restrict__ out_b, short* As, short* Bs) {
  const int tid  = threadIdx.x;
  const int wid  = tid >> 6, lane = tid & 63;
  const int wr   = (wid >> 1) * 32, wc = (wid & 1) * 32;
  const int srow = tid >> 2, schunk = (tid & 3) * 8;
  const int fr   = lane & 15, fk = (lane >> 4) * 8;

  f32x4 acc[2][2];
#pragma unroll
  for (int a = 0; a < 2; ++a)
#pragma unroll
    for (int b = 0; b < 2; ++b) acc[a][b] = (f32x4){0.f, 0.f, 0.f, 0.f};

  for (int kk = 0; kk < K; kk += 32) {
    float4 a0 = *(const float4*)&A[(size_t)(i0 + srow) * K + kk + schunk];
    float4 a1 = *(const float4*)&A[(size_t)(i0 + srow) * K + kk + schunk + 4];
    float4 b0 = *(const float4*)&B[(size_t)(j0 + srow) * K + kk + schunk];
    float4 b1 = *(const float4*)&B[(size_t)(j0 + srow) * K + kk + schunk + 4];
    s16x8 av, bv;
    av[0] = (short)f2b_bits(a0.x); av[1] = (short)f2b_bits(a0.y);
    av[2] = (short)f2b_bits(a0.z); av[3] = (short)f2b_bits(a0.w);
    av[4] = (short)f2b_bits(a1.x); av[5] = (short)f2b_bits(a1.y);
    av[6] = (short)f2b_bits(a1.z); av[7] = (short)f2b_bits(a1.w);
    bv[0] = (short)f2b_bits(b0.x); bv[1] = (short)f2b_bits(b0.y);
    bv[2] = (short)f2b_bits(b0.z); bv[3] = (short)f2b_bits(b0.w);
    bv[4] = (short)f2b_bits(b1.x); bv[5] = (short)f2b_bits(b1.y);
    bv[6] = (short)f2b_bits(b1.z); bv[7] = (short)f2b_bits(b1.w);
    *(s16x8*)&As[srow * 40 + schunk] = av;
    *(s16x8*)&Bs[srow * 40 + schunk] = bv;
    __syncthreads();
    gemm_mfma_body(As, Bs, acc, wr, wc, fr, fk);
    __syncthreads();
  }

  const int ecol = lane & 15, erow0 = (lane >> 4) * 4;
#pragma unroll
  for (int mi = 0; mi < 2; ++mi)
#pragma unroll
    for (int ni = 0; ni < 2; ++ni)
#pragma unroll
      for (int v = 0; v < 4; ++v) {
        int i = i0 + wr + mi * 16 + erow0 + v;
        int j = j0 + wc + ni * 16 + ecol;
        if (j < N) out_b[(size_t)i * N + j] = f2b_bits(acc[mi][ni][v]);
      }
}

// ================= D1: build_adj + converts + weight-fusion GEMMs =================
// blocks [0,16384): incidence scan -> noe/eon via atomics
// blocks [16384, 17728): f32->bf16 converts (x | ea | wout)
// blocks [17728, 17780): fuse_w with inline f32->bf16 (F = ipw@wlin^T, G = Wk@wedge^T)
__global__ __launch_bounds__(256) void mega1(
    const float* __restrict__ inc,
    int* __restrict__ cnt_e, int* __restrict__ cnt_n,
    int* __restrict__ noe, int* __restrict__ eon,
    const float* __restrict__ x, const float* __restrict__ ea,
    const float* __restrict__ wout,
    unsigned short* __restrict__ xb, unsigned short* __restrict__ eab,
    unsigned short* __restrict__ woutb,
    const float* __restrict__ ipw, const float* __restrict__ wlin,
    const float* __restrict__ wedge,
    unsigned short* __restrict__ F, unsigned short* __restrict__ G) {
  __shared__ short As[64 * 40] __attribute__((aligned(16)));
  __shared__ short Bs[64 * 40] __attribute__((aligned(16)));
  const int bid = blockIdx.x;
  if (bid < 16384) {
    int t = bid * 256 + threadIdx.x;
    float4 v = ((const float4*)inc)[t];
    int flat = t * 4;
    int e  = flat >> 12;
    int u0 = flat & 4095;
    float vals[4] = {v.x, v.y, v.z, v.w};
#pragma unroll
    for (int j = 0; j < 4; ++j) {
      if (vals[j] != 0.0f) {
        int u  = u0 + j;
        int pe = atomicAdd(&cnt_e[e], 1);
        noe[e * 8 + pe] = u;
        int pn = atomicAdd(&cnt_n[u], 1);
        eon[u * 8 + pn] = e;
      }
    }
    return;
  }
  if (bid < 17728) {
    int j = (bid - 16384) * 256 + threadIdx.x;
    const float* src; unsigned short* dst;
    if (j < 262144)      { src = x;    dst = xb; }
    else { j -= 262144;
    if (j < 65536)       { src = ea;   dst = eab; }
    else { j -= 65536;     src = wout; dst = woutb; } }
    float4 v = ((const float4*)src)[j];
    ushort4 o;
    o.x = f2b_bits(v.x); o.y = f2b_bits(v.y); o.z = f2b_bits(v.z); o.w = f2b_bits(v.w);
    ((ushort4*)dst)[j] = o;
    return;
  }
  int fb = bid - 17728;
  if (fb < 48) {
    gemm_tile_f32src(ipw, wlin, (fb >> 2) * 64, (fb & 3) * 64, 256, 256, F, As, Bs);
  } else {
    gemm_tile_f32src(ipw + 65536, wedge, (fb - 48) * 64, 0, 64, 256, G, As, Bs);
  }
}

// ================= D2: proj GEMM + Ke GEMM + pair_u builder =================
// blocks [0,768): [q|Kn|Vn] = x@F^T ; [768,1024): Ke = ea@G^T ; [1024,1088): pair_u
__global__ __launch_bounds__(256) void mega2(
    const unsigned short* __restrict__ x_bf, const unsigned short* __restrict__ F,
    const unsigned short* __restrict__ ea_bf, const unsigned short* __restrict__ G,
    unsigned short* __restrict__ Q, unsigned short* __restrict__ Kn,
    unsigned short* __restrict__ Vn, unsigned short* __restrict__ Ke,
    const float* __restrict__ ipb,
    const int* __restrict__ eon, const int* __restrict__ noe,
    int* __restrict__ pair_u) {
  __shared__ short As[64 * 40] __attribute__((aligned(16)));
  __shared__ short Bs[64 * 40] __attribute__((aligned(16)));
  const int bid = blockIdx.x;
  if (bid < 768) {
    // out_b=Q, out_b2=Kn, out_f reinterpreted as Vn (bf16) in MODE_PROJ
    gemm_tile(x_bf, F, (bid & 63) * 64, (bid >> 6) * 64, 768, 256,
              MODE_PROJ, (float*)Vn, Q, Kn, ipb, As, Bs);
  } else if (bid < 1024) {
    int r = bid - 768;
    gemm_tile(ea_bf, G, (r & 63) * 64, (r >> 6) * 64, 256, 64,
              MODE_PLAIN, nullptr, Ke, nullptr, nullptr, As, Bs);
  } else {
    // pair builder: 64 blocks = 256 waves; each wave fills 16 nodes
    // (round-4 BUG was here: one-wave-one-node covered only 256/4096 nodes)
    int wv = ((bid - 1024) * 256 + threadIdx.x) >> 6;   // 0..255
    int lane = threadIdx.x & 63;
#pragma unroll
    for (int r = 0; r < 16; ++r) {
      int n = wv * 16 + r;
      int e = eon[n * 8 + (lane >> 3)];
      pair_u[n * 64 + lane] = noe[e * 8 + (lane & 7)];
    }
  }
}

// ================= D3: attention — one wave per (node, head), no LDS, no barriers ====
__global__ __launch_bounds__(256) void attn_kernel(
    const unsigned short* __restrict__ Q, const unsigned short* __restrict__ Kn,
    const unsigned short* __restrict__ Vn, const unsigned short* __restrict__ Ke,
    const int* __restrict__ eon, const int* __restrict__ pair_u,
    unsigned short* __restrict__ ctx) {
  const int w = (blockIdx.x * 256 + threadIdx.x) >> 6;  // global wave id
  const int n = w >> 3, h = w & 7;
  const int lane = threadIdx.x & 63;
  const int rg = lane & 15, dchunk = lane >> 4;

  const int u = pair_u[n * 64 + lane];                  // coalesced 256B/wave
  const int e = eon[n * 8 + (lane >> 3)];               // 32B, broadcast segments

  // V gather: lane owns rows rg*4..rg*4+3, dims dchunk*8..+7
  int ur[4];
#pragma unroll
  for (int i = 0; i < 4; ++i) ur[i] = __shfl(u, rg * 4 + i, 64);
  u16x8 vstage[4];
#pragma unroll
  for (int i = 0; i < 4; ++i)
    vstage[i] = *(const u16x8*)(Vn + (size_t)ur[i] * 256 + h * 32 + dchunk * 8);

  // score for pair `lane`: q.(Kn[u]+Ke[e]); q pre-scaled+biased, Kn un-biased (cancels)
  const u16x8* kp = (const u16x8*)(Kn + (size_t)u * 256 + h * 32);
  const u16x8* ep = (const u16x8*)(Ke + (size_t)e * 256 + h * 32);
  const u16x8* qp = (const u16x8*)(Q  + (size_t)n * 256 + h * 32);
  float s = 0.f;
#pragma unroll
  for (int c = 0; c < 4; ++c) {
    u16x8 kv = kp[c], ev = ep[c], qv = qp[c];
#pragma unroll
    for (int j = 0; j < 8; ++j)
      s += b2f(qv[j]) * (b2f(kv[j]) + b2f(ev[j]));
  }

  // wave-wide softmax over 64 pairs
  float m = s;
#pragma unroll
  for (int off = 32; off >= 1; off >>= 1) m = fmaxf(m, __shfl_xor(m, off));
  float p = __expf(s - m);
  float sum = p;
#pragma unroll
  for (int off = 32; off >= 1; off >>= 1) sum += __shfl_xor(sum, off);
  const float a = __fdividef(p, sum);

  // PV in registers: weights via shfl, reduce over rg bits
  float acc[8];
#pragma unroll
  for (int j = 0; j < 8; ++j) acc[j] = 0.f;
#pragma unroll
  for (int i = 0; i < 4; ++i) {
    float pi = __shfl(a, rg * 4 + i, 64);
#pragma unroll
    for (int j = 0; j < 8; ++j) acc[j] += pi * b2f(vstage[i][j]);
  }
#pragma unroll
  for (int off = 1; off < 16; off <<= 1)
#pragma unroll
    for (int j = 0; j < 8; ++j) acc[j] += __shfl_xor(acc[j], off, 64);

  if (rg == 0) {
    u16x8 o;
#pragma unroll
    for (int j = 0; j < 8; ++j) o[j] = f2b_bits(acc[j]);
    *(u16x8*)(ctx + (size_t)n * 256 + h * 32 + dchunk * 8) = o;
  }
}

// ================= D4: output projection GEMM =================
__global__ __launch_bounds__(256) void gemm_out(
    const unsigned short* __restrict__ ctx, const unsigned short* __restrict__ wout_bf,
    float* __restrict__ out, const float* __restrict__ bias) {
  __shared__ short As[64 * 40] __attribute__((aligned(16)));
  __shared__ short Bs[64 * 40] __attribute__((aligned(16)));
  gemm_tile(ctx, wout_bf, blockIdx.x * 64, blockIdx.y * 64, 256, 256,
            MODE_OUT, out, nullptr, nullptr, bias, As, Bs);
}

// ================= workspace layout (bytes) =================
#define MB_ ((size_t)1048576)
#define OFF_Q      ((size_t)0)            // 2MB bf16
#define OFF_KN     (2*MB_)                // 2MB
#define OFF_VN     (4*MB_)                // 2MB
#define OFF_KE     (6*MB_)                // 2MB
#define OFF_CTX    (8*MB_)                // 2MB
#define OFF_XBF    (10*MB_)               // 2MB
#define OFF_EABF   (12*MB_)               // 512KB
#define OFF_WOUTBF (12*MB_+524288)        // 128KB
#define OFF_F      (13*MB_)               // 384KB
#define OFF_G      (13*MB_+524288)        // 32KB
#define OFF_PAIRU  (14*MB_)               // 1MB
#define OFF_CNTE   (15*MB_)               // 16KB
#define OFF_CNTN   (15*MB_+16384)         // 16KB
#define OFF_NOE    (15*MB_+32768)         // 128KB
#define OFF_EON    (15*MB_+163840)        // 128KB

extern "C" void kernel_launch(void* const* d_in, const int* in_sizes, int n_in,
                              void* d_out, int out_size, void* d_ws, size_t ws_size,
                              hipStream_t stream) {
  const float* x     = (const float*)d_in[0];
  const float* inc   = (const float*)d_in[1];
  const float* ea    = (const float*)d_in[2];
  const float* wlin  = (const float*)d_in[3];
  const float* wedge = (const float*)d_in[4];
  const float* ipw   = (const float*)d_in[5];
  const float* ipb   = (const float*)d_in[6];
  const float* wout  = (const float*)d_in[7];
  const float* outb  = (const float*)d_in[8];

  char* ws = (char*)d_ws;
  unsigned short* Q       = (unsigned short*)(ws + OFF_Q);
  unsigned short* Kn      = (unsigned short*)(ws + OFF_KN);
  unsigned short* Vn      = (unsigned short*)(ws + OFF_VN);
  unsigned short* Ke      = (unsigned short*)(ws + OFF_KE);
  unsigned short* ctx     = (unsigned short*)(ws + OFF_CTX);
  unsigned short* x_bf    = (unsigned short*)(ws + OFF_XBF);
  unsigned short* ea_bf   = (unsigned short*)(ws + OFF_EABF);
  unsigned short* wout_bf = (unsigned short*)(ws + OFF_WOUTBF);
  unsigned short* F       = (unsigned short*)(ws + OFF_F);
  unsigned short* G       = (unsigned short*)(ws + OFF_G);
  int*            cnt_e   = (int*)(ws + OFF_CNTE);
  int*            noe     = (int*)(ws + OFF_NOE);
  int*            eon     = (int*)(ws + OFF_EON);
  int*            pair_u  = (int*)(ws + OFF_PAIRU);

  hipMemsetAsync(ws + OFF_CNTE, 0, 32768, stream);   // cnt_e + cnt_n

  // D1: incidence scan + converts + weight-fusion GEMMs
  mega1<<<17780, 256, 0, stream>>>(inc, cnt_e, (int*)(ws + OFF_CNTN), noe, eon,
                                   x, ea, wout, x_bf, ea_bf, wout_bf,
                                   ipw, wlin, wedge, F, G);
  // D2: projections + Ke + pair_u builder
  mega2<<<1088, 256, 0, stream>>>(x_bf, F, ea_bf, G, Q, Kn, Vn, Ke, ipb,
                                  eon, noe, pair_u);
  // D3: attention (wave-autonomous)
  attn_kernel<<<8192, 256, 0, stream>>>(Q, Kn, Vn, Ke, eon, pair_u, ctx);
  // D4: output projection + bias + relu -> d_out (f32)
  gemm_out<<<dim3(64, 4), 256, 0, stream>>>(ctx, wout_bf, (float*)d_out, outb);
}